// Round 5
// baseline (14042.772 us; speedup 1.0000x reference)
//
#include <hip/hip_runtime.h>
#include <cstdint>

constexpr int Bn = 128, Tn = 1024, Dn = 64, Hn = 256, On = 128;
constexpr int HSL = 36;         // padded LDS slice stride (32 data + 4 pad) -> 2-way max
constexpr int HCSZ = 16 * HSL;  // concat state buffer: slices 0-7 = h1, 8-15 = h2

typedef float v2f __attribute__((ext_vector_type(2)));

__device__ __forceinline__ float fast_tanh(float x) {
  float e = __expf(2.0f * x);
  return 1.0f - 2.0f / (e + 1.0f);
}

// DPP butterfly sum over the 16-lane row (our 16 K-slices live in one DPP row).
// xor1 = quad_perm[1,0,3,2]=0xB1; xor2 = quad_perm[2,3,0,1]=0x4E;
// xor4 == ROW_HALF_MIRROR (0x141) after quad-uniformity; xor8 == ROW_MIRROR (0x140)
// after 8-uniformity. Pure VALU — zero LDS-pipe traffic.
// ctrl must be an immediate -> template parameter.
template <int CTRL>
__device__ __forceinline__ float dpp_add(float v) {
  int s = __builtin_amdgcn_update_dpp(0, __float_as_int(v), CTRL, 0xF, 0xF, true);
  return v + __int_as_float(s);
}
__device__ __forceinline__ float row16_sum(float v) {
  v = dpp_add<0xB1>(v);
  v = dpp_add<0x4E>(v);
  v = dpp_add<0x141>(v);
  v = dpp_add<0x140>(v);
  return v;
}

// ---------------------------------------------------------------------------
// Fused 2-layer RNN scan. One WG (512 thr) per batch element.
// Thread (cg = tid>>4 -> cols [8cg,8cg+8), ks = tid&15 -> K-slice).
// Per step: L1 (K=256 Wh1 + 64 Wx1) -> h1_t; barrier; L2 (K=512 over
// [h1_t | h2_{t-1}] vs [Wx2 ; Wh2]) -> h2_t. ONE barrier per step.
// All weights VGPR-resident as k-paired v2f (v_pk_fma_f32).
// ---------------------------------------------------------------------------
__global__ __launch_bounds__(512, 1) void rnn_fused_kernel(
    const float* __restrict__ x,    // [B,T,64]
    const float* __restrict__ Wx1,  // [64,256]
    const float* __restrict__ Wh1,  // [256,256]
    const float* __restrict__ b1,   // [256]
    const float* __restrict__ Wx2,  // [256,256]
    const float* __restrict__ Wh2,  // [256,256]
    const float* __restrict__ b2,   // [256]
    float* __restrict__ hfinal) {   // [B,256]
  __shared__ alignas(16) float hc[2][HCSZ];
  __shared__ alignas(16) float xs[2][2048];  // 32-step x blocks, double-buffered
  const int tid = threadIdx.x;
  const int ks = tid & 15;
  const int cg = tid >> 4;
  const int col0 = 8 * cg;
  const int b = blockIdx.x;
  const float* xb = x + (size_t)b * Tn * Dn;

  // ---- weights -> VGPRs (k-paired) ----
  v2f w1h[8][8];  // Wh1 rows [16ks,16ks+16)
  #pragma unroll
  for (int p = 0; p < 8; ++p) {
    const float* r0 = Wh1 + (size_t)(16 * ks + 2 * p) * Hn + col0;
    float4 a0 = *(const float4*)r0, a1 = *(const float4*)(r0 + 4);
    float4 c0 = *(const float4*)(r0 + Hn), c1 = *(const float4*)(r0 + Hn + 4);
    w1h[p][0] = (v2f){a0.x, c0.x}; w1h[p][1] = (v2f){a0.y, c0.y};
    w1h[p][2] = (v2f){a0.z, c0.z}; w1h[p][3] = (v2f){a0.w, c0.w};
    w1h[p][4] = (v2f){a1.x, c1.x}; w1h[p][5] = (v2f){a1.y, c1.y};
    w1h[p][6] = (v2f){a1.z, c1.z}; w1h[p][7] = (v2f){a1.w, c1.w};
  }
  v2f w1x[2][8];  // Wx1 rows [4ks,4ks+4)
  #pragma unroll
  for (int p = 0; p < 2; ++p) {
    const float* r0 = Wx1 + (size_t)(4 * ks + 2 * p) * Hn + col0;
    float4 a0 = *(const float4*)r0, a1 = *(const float4*)(r0 + 4);
    float4 c0 = *(const float4*)(r0 + Hn), c1 = *(const float4*)(r0 + Hn + 4);
    w1x[p][0] = (v2f){a0.x, c0.x}; w1x[p][1] = (v2f){a0.y, c0.y};
    w1x[p][2] = (v2f){a0.z, c0.z}; w1x[p][3] = (v2f){a0.w, c0.w};
    w1x[p][4] = (v2f){a1.x, c1.x}; w1x[p][5] = (v2f){a1.y, c1.y};
    w1x[p][6] = (v2f){a1.z, c1.z}; w1x[p][7] = (v2f){a1.w, c1.w};
  }
  v2f w2[16][8];  // concat rows [32ks,32ks+32): Wx2 (ks<8) / Wh2 (ks>=8)
  {
    const float* W2base = (ks < 8) ? (Wx2 + (size_t)(32 * ks) * Hn)
                                   : (Wh2 + (size_t)(32 * (ks - 8)) * Hn);
    #pragma unroll
    for (int p = 0; p < 16; ++p) {
      const float* r0 = W2base + (size_t)(2 * p) * Hn + col0;
      float4 a0 = *(const float4*)r0, a1 = *(const float4*)(r0 + 4);
      float4 c0 = *(const float4*)(r0 + Hn), c1 = *(const float4*)(r0 + Hn + 4);
      w2[p][0] = (v2f){a0.x, c0.x}; w2[p][1] = (v2f){a0.y, c0.y};
      w2[p][2] = (v2f){a0.z, c0.z}; w2[p][3] = (v2f){a0.w, c0.w};
      w2[p][4] = (v2f){a1.x, c1.x}; w2[p][5] = (v2f){a1.y, c1.y};
      w2[p][6] = (v2f){a1.z, c1.z}; w2[p][7] = (v2f){a1.w, c1.w};
    }
  }

  // post-reduce column split: lane handles cols cA=col0+2q, cB=cA+1 (q=ks&3)
  const int q = ks & 3;
  const float bias1A = b1[col0 + 2 * q], bias1B = b1[col0 + 2 * q + 1];
  const float bias2A = b2[col0 + 2 * q], bias2B = b2[col0 + 2 * q + 1];
  const bool writer = (ks < 4);
  // LDS dword offset of this thread's (cA,cB) pair within an 8-slice half
  const int woff = (cg >> 2) * HSL + 8 * (cg & 3) + 2 * q;

  for (int i = tid; i < 2 * HCSZ; i += 512) (&hc[0][0])[i] = 0.f;
  *(float4*)&xs[0][4 * tid] = *(const float4*)(xb + 4 * tid);  // block 0
  float4 xr = *(const float4*)(xb + 2048 + 4 * tid);           // block 1
  __syncthreads();

  for (int blk = 0; blk < 32; ++blk) {
    const int xcur = blk & 1;
    for (int s = 0; s < 32; ++s) {
      const int t = 32 * blk + s;
      const int cu = t & 1, nx = cu ^ 1;

      // ---------- L1: h1_t = tanh(x_t@Wx1 + h1_{t-1}@Wh1 + b1) ----------
      v2f a0 = (v2f){0.f, 0.f}, a1 = a0, a2 = a0, a3 = a0,
          a4 = a0, a5 = a0, a6 = a0, a7 = a0;
      {
        const float* hsrc = &hc[cu][(ks >> 1) * HSL + 16 * (ks & 1)];
        #pragma unroll
        for (int i = 0; i < 4; ++i) {
          float4 hv = ((const float4*)hsrc)[i];
          v2f hA = (v2f){hv.x, hv.y}, hB = (v2f){hv.z, hv.w};
          a0 = __builtin_elementwise_fma(hA, w1h[2*i][0], a0);
          a1 = __builtin_elementwise_fma(hA, w1h[2*i][1], a1);
          a2 = __builtin_elementwise_fma(hA, w1h[2*i][2], a2);
          a3 = __builtin_elementwise_fma(hA, w1h[2*i][3], a3);
          a4 = __builtin_elementwise_fma(hA, w1h[2*i][4], a4);
          a5 = __builtin_elementwise_fma(hA, w1h[2*i][5], a5);
          a6 = __builtin_elementwise_fma(hA, w1h[2*i][6], a6);
          a7 = __builtin_elementwise_fma(hA, w1h[2*i][7], a7);
          a0 = __builtin_elementwise_fma(hB, w1h[2*i+1][0], a0);
          a1 = __builtin_elementwise_fma(hB, w1h[2*i+1][1], a1);
          a2 = __builtin_elementwise_fma(hB, w1h[2*i+1][2], a2);
          a3 = __builtin_elementwise_fma(hB, w1h[2*i+1][3], a3);
          a4 = __builtin_elementwise_fma(hB, w1h[2*i+1][4], a4);
          a5 = __builtin_elementwise_fma(hB, w1h[2*i+1][5], a5);
          a6 = __builtin_elementwise_fma(hB, w1h[2*i+1][6], a6);
          a7 = __builtin_elementwise_fma(hB, w1h[2*i+1][7], a7);
        }
        float4 xv = *(const float4*)&xs[xcur][(s << 6) + 4 * ks];
        v2f xA = (v2f){xv.x, xv.y}, xB = (v2f){xv.z, xv.w};
        a0 = __builtin_elementwise_fma(xA, w1x[0][0], a0);
        a1 = __builtin_elementwise_fma(xA, w1x[0][1], a1);
        a2 = __builtin_elementwise_fma(xA, w1x[0][2], a2);
        a3 = __builtin_elementwise_fma(xA, w1x[0][3], a3);
        a4 = __builtin_elementwise_fma(xA, w1x[0][4], a4);
        a5 = __builtin_elementwise_fma(xA, w1x[0][5], a5);
        a6 = __builtin_elementwise_fma(xA, w1x[0][6], a6);
        a7 = __builtin_elementwise_fma(xA, w1x[0][7], a7);
        a0 = __builtin_elementwise_fma(xB, w1x[1][0], a0);
        a1 = __builtin_elementwise_fma(xB, w1x[1][1], a1);
        a2 = __builtin_elementwise_fma(xB, w1x[1][2], a2);
        a3 = __builtin_elementwise_fma(xB, w1x[1][3], a3);
        a4 = __builtin_elementwise_fma(xB, w1x[1][4], a4);
        a5 = __builtin_elementwise_fma(xB, w1x[1][5], a5);
        a6 = __builtin_elementwise_fma(xB, w1x[1][6], a6);
        a7 = __builtin_elementwise_fma(xB, w1x[1][7], a7);
      }
      {
        float s0 = row16_sum(a0.x + a0.y), s1 = row16_sum(a1.x + a1.y);
        float s2 = row16_sum(a2.x + a2.y), s3 = row16_sum(a3.x + a3.y);
        float s4 = row16_sum(a4.x + a4.y), s5 = row16_sum(a5.x + a5.y);
        float s6 = row16_sum(a6.x + a6.y), s7 = row16_sum(a7.x + a7.y);
        float tA0 = (q & 1) ? s2 : s0, tA1 = (q & 1) ? s6 : s4;
        float sA = (q & 2) ? tA1 : tA0;
        float tB0 = (q & 1) ? s3 : s1, tB1 = (q & 1) ? s7 : s5;
        float sB = (q & 2) ? tB1 : tB0;
        float h1A = fast_tanh(sA + bias1A);
        float h1B = fast_tanh(sB + bias1B);
        if (writer) *(float2*)&hc[nx][woff] = make_float2(h1A, h1B);
      }
      // stage next x block (written before the barrier; read after it)
      if (s == 31 && blk < 31) {
        *(float4*)&xs[xcur ^ 1][4 * tid] = xr;
        if (blk < 30) xr = *(const float4*)(xb + (size_t)(blk + 2) * 2048 + 4 * tid);
      }
      __syncthreads();  // the ONLY barrier per step

      // ---------- L2: h2_t = tanh(h1_t@Wx2 + h2_{t-1}@Wh2 + b2) ----------
      a0 = (v2f){0.f, 0.f}; a1 = a0; a2 = a0; a3 = a0;
      a4 = a0; a5 = a0; a6 = a0; a7 = a0;
      {
        const float* hsrc = (ks < 8) ? &hc[nx][ks * HSL] : &hc[cu][ks * HSL];
        #pragma unroll
        for (int i = 0; i < 8; ++i) {
          float4 hv = ((const float4*)hsrc)[i];
          v2f hA = (v2f){hv.x, hv.y}, hB = (v2f){hv.z, hv.w};
          a0 = __builtin_elementwise_fma(hA, w2[2*i][0], a0);
          a1 = __builtin_elementwise_fma(hA, w2[2*i][1], a1);
          a2 = __builtin_elementwise_fma(hA, w2[2*i][2], a2);
          a3 = __builtin_elementwise_fma(hA, w2[2*i][3], a3);
          a4 = __builtin_elementwise_fma(hA, w2[2*i][4], a4);
          a5 = __builtin_elementwise_fma(hA, w2[2*i][5], a5);
          a6 = __builtin_elementwise_fma(hA, w2[2*i][6], a6);
          a7 = __builtin_elementwise_fma(hA, w2[2*i][7], a7);
          a0 = __builtin_elementwise_fma(hB, w2[2*i+1][0], a0);
          a1 = __builtin_elementwise_fma(hB, w2[2*i+1][1], a1);
          a2 = __builtin_elementwise_fma(hB, w2[2*i+1][2], a2);
          a3 = __builtin_elementwise_fma(hB, w2[2*i+1][3], a3);
          a4 = __builtin_elementwise_fma(hB, w2[2*i+1][4], a4);
          a5 = __builtin_elementwise_fma(hB, w2[2*i+1][5], a5);
          a6 = __builtin_elementwise_fma(hB, w2[2*i+1][6], a6);
          a7 = __builtin_elementwise_fma(hB, w2[2*i+1][7], a7);
        }
      }
      {
        float s0 = row16_sum(a0.x + a0.y), s1 = row16_sum(a1.x + a1.y);
        float s2 = row16_sum(a2.x + a2.y), s3 = row16_sum(a3.x + a3.y);
        float s4 = row16_sum(a4.x + a4.y), s5 = row16_sum(a5.x + a5.y);
        float s6 = row16_sum(a6.x + a6.y), s7 = row16_sum(a7.x + a7.y);
        float tA0 = (q & 1) ? s2 : s0, tA1 = (q & 1) ? s6 : s4;
        float sA = (q & 2) ? tA1 : tA0;
        float tB0 = (q & 1) ? s3 : s1, tB1 = (q & 1) ? s7 : s5;
        float sB = (q & 2) ? tB1 : tB0;
        float h2A = fast_tanh(sA + bias2A);
        float h2B = fast_tanh(sB + bias2B);
        if (writer) *(float2*)&hc[nx][8 * HSL + woff] = make_float2(h2A, h2B);
      }
      // no trailing barrier: next step's L1 reads h1 written before THIS
      // step's barrier; h2_t readers (next L2) are behind the next barrier.
    }
  }
  __syncthreads();
  if (tid < Hn) {
    // t=1023: cu=1, nx=0 -> final state in hc[0]
    float v = hc[0][(8 + (tid >> 5)) * HSL + (tid & 31)];
    hfinal[(size_t)b * Hn + tid] = v;
  }
}

// ---------------------------------------------------------------------------
// Head: out = softmax(h2_T @ Wd + bd). One WG (128 thr) per batch row.
// ---------------------------------------------------------------------------
__global__ __launch_bounds__(128) void head_kernel(
    const float* __restrict__ hfinal,  // [B,256]
    const float* __restrict__ Wd,      // [256,128]
    const float* __restrict__ bd,      // [128]
    float* __restrict__ out) {         // [B,128]
  __shared__ float hrow[Hn];
  __shared__ float red[On];
  const int o = threadIdx.x;
  const int b = blockIdx.x;
  hrow[o] = hfinal[(size_t)b * Hn + o];
  hrow[o + 128] = hfinal[(size_t)b * Hn + 128 + o];
  __syncthreads();
  float acc = bd[o];
  #pragma unroll 8
  for (int k = 0; k < Hn; ++k) acc = fmaf(hrow[k], Wd[(size_t)k * On + o], acc);
  red[o] = acc;
  __syncthreads();
  #pragma unroll
  for (int s = 64; s > 0; s >>= 1) {
    if (o < s) red[o] = fmaxf(red[o], red[o + s]);
    __syncthreads();
  }
  const float mx = red[0];
  __syncthreads();
  const float e = __expf(acc - mx);
  red[o] = e;
  __syncthreads();
  #pragma unroll
  for (int s = 64; s > 0; s >>= 1) {
    if (o < s) red[o] += red[o + s];
    __syncthreads();
  }
  out[(size_t)b * On + o] = e / red[0];
}

// ---------------------------------------------------------------------------
extern "C" void kernel_launch(void* const* d_in, const int* in_sizes, int n_in,
                              void* d_out, int out_size, void* d_ws, size_t ws_size,
                              hipStream_t stream) {
  const float* x   = (const float*)d_in[0];
  const float* Wx1 = (const float*)d_in[1];
  const float* Wh1 = (const float*)d_in[2];
  const float* b1  = (const float*)d_in[3];
  const float* Wx2 = (const float*)d_in[4];
  const float* Wh2 = (const float*)d_in[5];
  const float* b2  = (const float*)d_in[6];
  const float* Wd  = (const float*)d_in[7];
  const float* bd  = (const float*)d_in[8];
  float* out = (float*)d_out;

  float* hfinal = (float*)d_ws;  // [B,256]

  rnn_fused_kernel<<<Bn, 512, 0, stream>>>(x, Wx1, Wh1, b1, Wx2, Wh2, b2, hfinal);
  head_kernel<<<Bn, 128, 0, stream>>>(hfinal, Wd, bd, out);
}

// Round 6
// 1619.596 us; speedup vs baseline: 8.6705x; 8.6705x over previous
//
#include <hip/hip_runtime.h>
#include <cstdint>

constexpr int Bn = 128, Tn = 1024, Dn = 64, Hn = 256, On = 128;
constexpr int HSL = 36;  // padded LDS slice stride (32 data + 4 pad)

typedef float v2f __attribute__((ext_vector_type(2)));

__device__ __forceinline__ float fast_tanh(float x) {
  float e = __expf(2.0f * x);
  return 1.0f - 2.0f / (e + 1.0f);
}

// DPP butterfly sum over 16-lane rows (K-slices ks = tid&15 occupy one DPP row).
// HW-validated in R5 (fused kernel passed with this exact reduction).
template <int CTRL>
__device__ __forceinline__ float dpp_add(float v) {
  int s = __builtin_amdgcn_update_dpp(0, __float_as_int(v), CTRL, 0xF, 0xF, true);
  return v + __int_as_float(s);
}
__device__ __forceinline__ float row16_sum(float v) {
  v = dpp_add<0xB1>(v);   // quad_perm xor1
  v = dpp_add<0x4E>(v);   // quad_perm xor2
  v = dpp_add<0x141>(v);  // ROW_HALF_MIRROR == xor4 (post quad-uniformity)
  v = dpp_add<0x140>(v);  // ROW_MIRROR == xor8 (post 8-uniformity)
  return v;
}

// select s[ks&7] from 8 reduced sums (7 cndmask)
__device__ __forceinline__ float sel8(int ks, float s0, float s1, float s2,
                                      float s3, float s4, float s5, float s6,
                                      float s7) {
  float u0 = (ks & 1) ? s1 : s0;
  float u1 = (ks & 1) ? s3 : s2;
  float u2 = (ks & 1) ? s5 : s4;
  float u3 = (ks & 1) ? s7 : s6;
  float v0 = (ks & 2) ? u1 : u0;
  float v1 = (ks & 2) ? u3 : u2;
  return (ks & 4) ? v1 : v0;
}

// ---------------------------------------------------------------------------
// Scan 1: one WG (512 thr) per batch element. Thread (cg=tid>>4 -> cols
// [8cg,8cg+8), ks=tid&15 -> Wh rows [16ks,16ks+16) + Wx rows [4ks,4ks+4)).
// Weights k-paired in VGPRs (v_pk_fma_f32, 160 f32/thread). h broadcast via
// padded LDS (2-way max). 16-lane DPP reduction (no LDS). x staged per
// 32-step block; h1 flushed to global per 8-step group.
// ---------------------------------------------------------------------------
__global__ __launch_bounds__(512, 2) void scan1_kernel(
    const float* __restrict__ x,    // [B,T,64]
    const float* __restrict__ Wx1,  // [64,256]
    const float* __restrict__ Wh1,  // [256,256]
    const float* __restrict__ b1,   // [256]
    float* __restrict__ h1out) {    // [B,T,256]
  __shared__ alignas(16) float hc[2][8 * HSL];
  __shared__ alignas(16) float xs[2][2048];
  const int tid = threadIdx.x;
  const int ks = tid & 15;
  const int cg = tid >> 4;
  const int col0 = 8 * cg;
  const int b = blockIdx.x;
  const float* xb = x + (size_t)b * Tn * Dn;
  float* hb = h1out + (size_t)b * Tn * Hn;

  v2f wh[8][8];  // Wh1 row-pairs (16ks+2p, 16ks+2p+1) x 8 cols
  #pragma unroll
  for (int p = 0; p < 8; ++p) {
    const float* r0 = Wh1 + (size_t)(16 * ks + 2 * p) * Hn + col0;
    float4 a0 = *(const float4*)r0, a1 = *(const float4*)(r0 + 4);
    float4 c0 = *(const float4*)(r0 + Hn), c1 = *(const float4*)(r0 + Hn + 4);
    wh[p][0] = (v2f){a0.x, c0.x}; wh[p][1] = (v2f){a0.y, c0.y};
    wh[p][2] = (v2f){a0.z, c0.z}; wh[p][3] = (v2f){a0.w, c0.w};
    wh[p][4] = (v2f){a1.x, c1.x}; wh[p][5] = (v2f){a1.y, c1.y};
    wh[p][6] = (v2f){a1.z, c1.z}; wh[p][7] = (v2f){a1.w, c1.w};
  }
  v2f wx[2][8];  // Wx1 row-pairs (4ks+2p, 4ks+2p+1)
  #pragma unroll
  for (int p = 0; p < 2; ++p) {
    const float* r0 = Wx1 + (size_t)(4 * ks + 2 * p) * Hn + col0;
    float4 a0 = *(const float4*)r0, a1 = *(const float4*)(r0 + 4);
    float4 c0 = *(const float4*)(r0 + Hn), c1 = *(const float4*)(r0 + Hn + 4);
    wx[p][0] = (v2f){a0.x, c0.x}; wx[p][1] = (v2f){a0.y, c0.y};
    wx[p][2] = (v2f){a0.z, c0.z}; wx[p][3] = (v2f){a0.w, c0.w};
    wx[p][4] = (v2f){a1.x, c1.x}; wx[p][5] = (v2f){a1.y, c1.y};
    wx[p][6] = (v2f){a1.z, c1.z}; wx[p][7] = (v2f){a1.w, c1.w};
  }
  const int jcol = col0 + (ks & 7);
  const float bj = b1[jcol];
  const bool writer = (ks < 8);
  const int sidx = (jcol >> 5) * HSL + (jcol & 31);
  const int rbase = (ks >> 1) * HSL + ((ks & 1) << 4);  // h-read base (2-way banks)

  for (int i = tid; i < 2 * 8 * HSL; i += 512) (&hc[0][0])[i] = 0.f;
  *(float4*)&xs[0][4 * tid] = *(const float4*)(xb + 4 * tid);
  __syncthreads();

  float hreg[8];
  float4 xr = make_float4(0.f, 0.f, 0.f, 0.f);
  for (int t8 = 0; t8 < 128; ++t8) {
    const int xcur = (t8 >> 2) & 1;
    #pragma unroll
    for (int s = 0; s < 8; ++s) {
      const int t = t8 * 8 + s;
      const int cu = s & 1, nx = cu ^ 1;
      if (s == 0 && (t8 & 3) == 0 && t8 < 124)
        xr = *(const float4*)(xb + (size_t)((t8 >> 2) + 1) * 2048 + 4 * tid);

      v2f a0 = (v2f){0.f, 0.f}, a1 = a0, a2 = a0, a3 = a0,
          a4 = a0, a5 = a0, a6 = a0, a7 = a0;
      const float4* h4 = (const float4*)&hc[cu][rbase];
      #pragma unroll
      for (int qq = 0; qq < 4; ++qq) {
        float4 hv = h4[qq];
        v2f hA = (v2f){hv.x, hv.y}, hB = (v2f){hv.z, hv.w};
        a0 = __builtin_elementwise_fma(hA, wh[2*qq][0], a0);
        a1 = __builtin_elementwise_fma(hA, wh[2*qq][1], a1);
        a2 = __builtin_elementwise_fma(hA, wh[2*qq][2], a2);
        a3 = __builtin_elementwise_fma(hA, wh[2*qq][3], a3);
        a4 = __builtin_elementwise_fma(hA, wh[2*qq][4], a4);
        a5 = __builtin_elementwise_fma(hA, wh[2*qq][5], a5);
        a6 = __builtin_elementwise_fma(hA, wh[2*qq][6], a6);
        a7 = __builtin_elementwise_fma(hA, wh[2*qq][7], a7);
        a0 = __builtin_elementwise_fma(hB, wh[2*qq+1][0], a0);
        a1 = __builtin_elementwise_fma(hB, wh[2*qq+1][1], a1);
        a2 = __builtin_elementwise_fma(hB, wh[2*qq+1][2], a2);
        a3 = __builtin_elementwise_fma(hB, wh[2*qq+1][3], a3);
        a4 = __builtin_elementwise_fma(hB, wh[2*qq+1][4], a4);
        a5 = __builtin_elementwise_fma(hB, wh[2*qq+1][5], a5);
        a6 = __builtin_elementwise_fma(hB, wh[2*qq+1][6], a6);
        a7 = __builtin_elementwise_fma(hB, wh[2*qq+1][7], a7);
      }
      {
        float4 xv = *(const float4*)&xs[xcur][((t & 31) << 6) + 4 * ks];
        v2f xA = (v2f){xv.x, xv.y}, xB = (v2f){xv.z, xv.w};
        a0 = __builtin_elementwise_fma(xA, wx[0][0], a0);
        a1 = __builtin_elementwise_fma(xA, wx[0][1], a1);
        a2 = __builtin_elementwise_fma(xA, wx[0][2], a2);
        a3 = __builtin_elementwise_fma(xA, wx[0][3], a3);
        a4 = __builtin_elementwise_fma(xA, wx[0][4], a4);
        a5 = __builtin_elementwise_fma(xA, wx[0][5], a5);
        a6 = __builtin_elementwise_fma(xA, wx[0][6], a6);
        a7 = __builtin_elementwise_fma(xA, wx[0][7], a7);
        a0 = __builtin_elementwise_fma(xB, wx[1][0], a0);
        a1 = __builtin_elementwise_fma(xB, wx[1][1], a1);
        a2 = __builtin_elementwise_fma(xB, wx[1][2], a2);
        a3 = __builtin_elementwise_fma(xB, wx[1][3], a3);
        a4 = __builtin_elementwise_fma(xB, wx[1][4], a4);
        a5 = __builtin_elementwise_fma(xB, wx[1][5], a5);
        a6 = __builtin_elementwise_fma(xB, wx[1][6], a6);
        a7 = __builtin_elementwise_fma(xB, wx[1][7], a7);
      }
      float s0 = row16_sum(a0.x + a0.y), s1 = row16_sum(a1.x + a1.y);
      float s2 = row16_sum(a2.x + a2.y), s3 = row16_sum(a3.x + a3.y);
      float s4 = row16_sum(a4.x + a4.y), s5 = row16_sum(a5.x + a5.y);
      float s6 = row16_sum(a6.x + a6.y), s7 = row16_sum(a7.x + a7.y);
      float h = fast_tanh(sel8(ks, s0, s1, s2, s3, s4, s5, s6, s7) + bj);
      if (writer) hc[nx][sidx] = h;
      hreg[s] = h;
      if (s == 7) {
        if (writer) {
          float* dst = hb + (size_t)(t - 7) * Hn + jcol;
          #pragma unroll
          for (int i = 0; i < 8; ++i) dst[i * Hn] = hreg[i];
        }
        if ((t8 & 3) == 3 && t8 < 127) *(float4*)&xs[xcur ^ 1][4 * tid] = xr;
      }
      __syncthreads();  // single barrier per step (double-buffered hc/xs)
    }
  }
}

// ---------------------------------------------------------------------------
// GEMM: u2 = h1 @ Wx2 + b2. M=131072, N=K=256. WG=256 thr, M-block 128.
// 2D register tile 16 rows x 8 cols/thread; A staged k-major + W chunk in LDS.
// In-place safe: WG reads only its own 128 rows, epilogue after all chunks.
// ---------------------------------------------------------------------------
__global__ __launch_bounds__(256, 2) void gemm_rt_kernel(
    const float* A,                  // [M,256] (aliases out)
    const float* __restrict__ W,     // [256,256]
    const float* __restrict__ bias,  // [256]
    float* out) {                    // [M,256]
  __shared__ alignas(16) float At[32][128];  // k-major A chunk, 16 KB
  __shared__ alignas(16) float Wt[32][256];  // W chunk, 32 KB
  const int tid = threadIdx.x;
  const int tn = tid & 31;   // cols 8tn..8tn+8
  const int tm = tid >> 5;   // rows 16tm..16tm+16
  const size_t m0 = (size_t)blockIdx.x * 128;

  const int sm = tid & 127;          // A stage: row
  const int sk = (tid >> 7) * 16;    // A stage: k-half
  const int wk = tid >> 3;           // W stage: k row (32)
  const int wc = (tid & 7) * 4;      // W stage: col base (stride 32)

  float acc[16][8];
  #pragma unroll
  for (int r = 0; r < 16; ++r)
    #pragma unroll
    for (int c = 0; c < 8; ++c) acc[r][c] = 0.f;

  for (int kc = 0; kc < 256; kc += 32) {
    float4 av[4], wv[8];
    #pragma unroll
    for (int i = 0; i < 4; ++i)
      av[i] = *(const float4*)(A + (m0 + sm) * 256 + kc + sk + 4 * i);
    #pragma unroll
    for (int i = 0; i < 8; ++i)
      wv[i] = *(const float4*)(W + (size_t)(kc + wk) * 256 + wc + 32 * i);
    __syncthreads();  // protect previous chunk's LDS reads
    #pragma unroll
    for (int i = 0; i < 4; ++i) {
      At[sk + 4 * i + 0][sm] = av[i].x;
      At[sk + 4 * i + 1][sm] = av[i].y;
      At[sk + 4 * i + 2][sm] = av[i].z;
      At[sk + 4 * i + 3][sm] = av[i].w;
    }
    #pragma unroll
    for (int i = 0; i < 8; ++i) *(float4*)&Wt[wk][wc + 32 * i] = wv[i];
    __syncthreads();
    for (int k = 0; k < 32; ++k) {
      float ar[16];
      #pragma unroll
      for (int i = 0; i < 4; ++i) {
        float4 a = *(const float4*)&At[k][16 * tm + 4 * i];
        ar[4 * i + 0] = a.x; ar[4 * i + 1] = a.y;
        ar[4 * i + 2] = a.z; ar[4 * i + 3] = a.w;
      }
      float4 w0 = *(const float4*)&Wt[k][8 * tn];
      float4 w1 = *(const float4*)&Wt[k][8 * tn + 4];
      const float wr[8] = {w0.x, w0.y, w0.z, w0.w, w1.x, w1.y, w1.z, w1.w};
      #pragma unroll
      for (int r = 0; r < 16; ++r)
        #pragma unroll
        for (int c = 0; c < 8; ++c) acc[r][c] = fmaf(ar[r], wr[c], acc[r][c]);
    }
  }
  float4 b0 = *(const float4*)(bias + 8 * tn);
  float4 b1v = *(const float4*)(bias + 8 * tn + 4);
  const float bb[8] = {b0.x, b0.y, b0.z, b0.w, b1v.x, b1v.y, b1v.z, b1v.w};
  #pragma unroll
  for (int r = 0; r < 16; ++r) {
    float* dst = out + (m0 + 16 * tm + r) * 256 + 8 * tn;
    float4 o0 = make_float4(acc[r][0] + bb[0], acc[r][1] + bb[1],
                            acc[r][2] + bb[2], acc[r][3] + bb[3]);
    float4 o1 = make_float4(acc[r][4] + bb[4], acc[r][5] + bb[5],
                            acc[r][6] + bb[6], acc[r][7] + bb[7]);
    *(float4*)dst = o0;
    *(float4*)(dst + 4) = o1;
  }
}

// ---------------------------------------------------------------------------
// Scan 2: h2_t = tanh(u2_t + h2_{t-1}@Wh2). Same structure as scan1 (K=256,
// no x term); u2 prefetched one 8-step group ahead into registers.
// ---------------------------------------------------------------------------
__global__ __launch_bounds__(512, 2) void scan2_kernel(
    const float* __restrict__ U,    // [B,T,256] = h1@Wx2 + b2
    const float* __restrict__ Wh2,  // [256,256]
    float* __restrict__ hfinal) {   // [B,256]
  __shared__ alignas(16) float hc[2][8 * HSL];
  const int tid = threadIdx.x;
  const int ks = tid & 15;
  const int cg = tid >> 4;
  const int col0 = 8 * cg;
  const int b = blockIdx.x;
  const float* Ub = U + (size_t)b * Tn * Hn;

  v2f wh[8][8];
  #pragma unroll
  for (int p = 0; p < 8; ++p) {
    const float* r0 = Wh2 + (size_t)(16 * ks + 2 * p) * Hn + col0;
    float4 a0 = *(const float4*)r0, a1 = *(const float4*)(r0 + 4);
    float4 c0 = *(const float4*)(r0 + Hn), c1 = *(const float4*)(r0 + Hn + 4);
    wh[p][0] = (v2f){a0.x, c0.x}; wh[p][1] = (v2f){a0.y, c0.y};
    wh[p][2] = (v2f){a0.z, c0.z}; wh[p][3] = (v2f){a0.w, c0.w};
    wh[p][4] = (v2f){a1.x, c1.x}; wh[p][5] = (v2f){a1.y, c1.y};
    wh[p][6] = (v2f){a1.z, c1.z}; wh[p][7] = (v2f){a1.w, c1.w};
  }
  const int jcol = col0 + (ks & 7);
  const bool writer = (ks < 8);
  const int sidx = (jcol >> 5) * HSL + (jcol & 31);
  const int rbase = (ks >> 1) * HSL + ((ks & 1) << 4);

  for (int i = tid; i < 2 * 8 * HSL; i += 512) (&hc[0][0])[i] = 0.f;
  __syncthreads();

  float ucur[8], unxt[8];
  if (writer) {
    #pragma unroll
    for (int i = 0; i < 8; ++i) ucur[i] = Ub[(size_t)i * Hn + jcol];
  }

  for (int t8 = 0; t8 < 128; ++t8) {
    #pragma unroll
    for (int s = 0; s < 8; ++s) {
      const int cu = s & 1, nx = cu ^ 1;
      if (s == 0 && writer && t8 < 127) {
        #pragma unroll
        for (int i = 0; i < 8; ++i)
          unxt[i] = Ub[(size_t)(t8 * 8 + 8 + i) * Hn + jcol];
      }
      v2f a0 = (v2f){0.f, 0.f}, a1 = a0, a2 = a0, a3 = a0,
          a4 = a0, a5 = a0, a6 = a0, a7 = a0;
      const float4* h4 = (const float4*)&hc[cu][rbase];
      #pragma unroll
      for (int qq = 0; qq < 4; ++qq) {
        float4 hv = h4[qq];
        v2f hA = (v2f){hv.x, hv.y}, hB = (v2f){hv.z, hv.w};
        a0 = __builtin_elementwise_fma(hA, wh[2*qq][0], a0);
        a1 = __builtin_elementwise_fma(hA, wh[2*qq][1], a1);
        a2 = __builtin_elementwise_fma(hA, wh[2*qq][2], a2);
        a3 = __builtin_elementwise_fma(hA, wh[2*qq][3], a3);
        a4 = __builtin_elementwise_fma(hA, wh[2*qq][4], a4);
        a5 = __builtin_elementwise_fma(hA, wh[2*qq][5], a5);
        a6 = __builtin_elementwise_fma(hA, wh[2*qq][6], a6);
        a7 = __builtin_elementwise_fma(hA, wh[2*qq][7], a7);
        a0 = __builtin_elementwise_fma(hB, wh[2*qq+1][0], a0);
        a1 = __builtin_elementwise_fma(hB, wh[2*qq+1][1], a1);
        a2 = __builtin_elementwise_fma(hB, wh[2*qq+1][2], a2);
        a3 = __builtin_elementwise_fma(hB, wh[2*qq+1][3], a3);
        a4 = __builtin_elementwise_fma(hB, wh[2*qq+1][4], a4);
        a5 = __builtin_elementwise_fma(hB, wh[2*qq+1][5], a5);
        a6 = __builtin_elementwise_fma(hB, wh[2*qq+1][6], a6);
        a7 = __builtin_elementwise_fma(hB, wh[2*qq+1][7], a7);
      }
      float s0 = row16_sum(a0.x + a0.y), s1 = row16_sum(a1.x + a1.y);
      float s2 = row16_sum(a2.x + a2.y), s3 = row16_sum(a3.x + a3.y);
      float s4 = row16_sum(a4.x + a4.y), s5 = row16_sum(a5.x + a5.y);
      float s6 = row16_sum(a6.x + a6.y), s7 = row16_sum(a7.x + a7.y);
      float h = fast_tanh(sel8(ks, s0, s1, s2, s3, s4, s5, s6, s7) + ucur[s]);
      if (writer) hc[nx][sidx] = h;
      if (s == 7) {
        #pragma unroll
        for (int i = 0; i < 8; ++i) ucur[i] = unxt[i];
      }
      __syncthreads();
    }
  }
  // t=1023 wrote hc[0]
  if (tid < Hn)
    hfinal[(size_t)b * Hn + tid] = hc[0][(tid >> 5) * HSL + (tid & 31)];
}

// ---------------------------------------------------------------------------
// Head: out = softmax(h2_T @ Wd + bd). One WG (128 thr) per batch row.
// ---------------------------------------------------------------------------
__global__ __launch_bounds__(128) void head_kernel(
    const float* __restrict__ hfinal,  // [B,256]
    const float* __restrict__ Wd,      // [256,128]
    const float* __restrict__ bd,      // [128]
    float* __restrict__ out) {         // [B,128]
  __shared__ float hrow[Hn];
  __shared__ float red[On];
  const int o = threadIdx.x;
  const int b = blockIdx.x;
  hrow[o] = hfinal[(size_t)b * Hn + o];
  hrow[o + 128] = hfinal[(size_t)b * Hn + 128 + o];
  __syncthreads();
  float acc = bd[o];
  #pragma unroll 8
  for (int k = 0; k < Hn; ++k) acc = fmaf(hrow[k], Wd[(size_t)k * On + o], acc);
  red[o] = acc;
  __syncthreads();
  #pragma unroll
  for (int s = 64; s > 0; s >>= 1) {
    if (o < s) red[o] = fmaxf(red[o], red[o + s]);
    __syncthreads();
  }
  const float mx = red[0];
  __syncthreads();
  const float e = __expf(acc - mx);
  red[o] = e;
  __syncthreads();
  #pragma unroll
  for (int s = 64; s > 0; s >>= 1) {
    if (o < s) red[o] += red[o + s];
    __syncthreads();
  }
  out[(size_t)b * On + o] = e / red[0];
}

// ---------------------------------------------------------------------------
extern "C" void kernel_launch(void* const* d_in, const int* in_sizes, int n_in,
                              void* d_out, int out_size, void* d_ws, size_t ws_size,
                              hipStream_t stream) {
  const float* x   = (const float*)d_in[0];
  const float* Wx1 = (const float*)d_in[1];
  const float* Wh1 = (const float*)d_in[2];
  const float* b1  = (const float*)d_in[3];
  const float* Wx2 = (const float*)d_in[4];
  const float* Wh2 = (const float*)d_in[5];
  const float* b2  = (const float*)d_in[6];
  const float* Wd  = (const float*)d_in[7];
  const float* bd  = (const float*)d_in[8];
  float* out = (float*)d_out;

  float* buf = (float*)d_ws;                   // h1 then (in-place) u2: [B*T*256]
  float* hfinal = buf + (size_t)Bn * Tn * Hn;  // [B*256]

  scan1_kernel<<<Bn, 512, 0, stream>>>(x, Wx1, Wh1, b1, buf);
  gemm_rt_kernel<<<(Bn * Tn) / 128, 256, 0, stream>>>(buf, Wx2, b2, buf);
  scan2_kernel<<<Bn, 512, 0, stream>>>(buf, Wh2, hfinal);
  head_kernel<<<Bn, 128, 0, stream>>>(hfinal, Wd, bd, out);
}

// Round 7
// 1472.609 us; speedup vs baseline: 9.5360x; 1.0998x over previous
//
#include <hip/hip_runtime.h>
#include <cstdint>

constexpr int Bn = 128, Tn = 1024, Dn = 64, Hn = 256, On = 128;
constexpr int HSL = 36;  // padded LDS slice stride (32 data + 4 pad)

typedef float v2f __attribute__((ext_vector_type(2)));

__device__ __forceinline__ float fast_tanh(float x) {
  float e = __expf(2.0f * x);
  return 1.0f - 2.0f / (e + 1.0f);
}

template <int CTRL>
__device__ __forceinline__ float dpp_add(float v) {
  int s = __builtin_amdgcn_update_dpp(0, __float_as_int(v), CTRL, 0xF, 0xF, true);
  return v + __int_as_float(s);
}
__device__ __forceinline__ float row16_sum(float v) {
  v = dpp_add<0xB1>(v);   // quad_perm xor1
  v = dpp_add<0x4E>(v);   // quad_perm xor2
  v = dpp_add<0x141>(v);  // ROW_HALF_MIRROR == xor4
  v = dpp_add<0x140>(v);  // ROW_MIRROR == xor8
  return v;
}

__device__ __forceinline__ float sel8(int ks, float s0, float s1, float s2,
                                      float s3, float s4, float s5, float s6,
                                      float s7) {
  float u0 = (ks & 1) ? s1 : s0;
  float u1 = (ks & 1) ? s3 : s2;
  float u2 = (ks & 1) ? s5 : s4;
  float u3 = (ks & 1) ? s7 : s6;
  float v0 = (ks & 2) ? u1 : u0;
  float v1 = (ks & 2) ? u3 : u2;
  return (ks & 4) ? v1 : v0;
}

// ---------------------------------------------------------------------------
// Stage 1 (256 WGs): WGs 0-127 = scan1 producer (R6 structure + release flag
// per 32-step block). WGs 128-255 = u2 consumer: Wx2 register-resident,
// spin-acquire on flag, stage h1 block to LDS, u2 = h1@Wx2+b2 written IN
// PLACE over h1. Deadlock-free: producers never wait; 256 WGs <= 256 CUs.
// ---------------------------------------------------------------------------
__global__ __launch_bounds__(512, 2) void stage1_kernel(
    const float* __restrict__ x,    // [B,T,64]
    const float* __restrict__ Wx1,  // [64,256]
    const float* __restrict__ Wh1,  // [256,256]
    const float* __restrict__ b1,   // [256]
    const float* __restrict__ Wx2,  // [256,256]
    const float* __restrict__ b2,   // [256]
    float* __restrict__ h1buf,      // [B,T,256] h1 then (in-place) u2
    int* __restrict__ flags) {      // [B] 32-step blocks published
  __shared__ alignas(16) float smem[32 * 8 * HSL];  // 36 KB, both roles carve
  const int tid = threadIdx.x;
  const int ks = tid & 15;
  const int cg = tid >> 4;
  const int col0 = 8 * cg;
  const int jcol = col0 + (ks & 7);
  const bool writer = (ks < 8);

  if (blockIdx.x < Bn) {
    // ================= ROLE A: scan1 producer =================
    const int b = blockIdx.x;
    const float* xb = x + (size_t)b * Tn * Dn;
    float* hb = h1buf + (size_t)b * Tn * Hn;
    float* hc0 = smem;          // [2][8*HSL] = 576 floats
    float* xs0 = smem + 576;    // [2][2048]

    v2f wh[8][8];
    #pragma unroll
    for (int p = 0; p < 8; ++p) {
      const float* r0 = Wh1 + (size_t)(16 * ks + 2 * p) * Hn + col0;
      float4 a0 = *(const float4*)r0, a1 = *(const float4*)(r0 + 4);
      float4 c0 = *(const float4*)(r0 + Hn), c1 = *(const float4*)(r0 + Hn + 4);
      wh[p][0] = (v2f){a0.x, c0.x}; wh[p][1] = (v2f){a0.y, c0.y};
      wh[p][2] = (v2f){a0.z, c0.z}; wh[p][3] = (v2f){a0.w, c0.w};
      wh[p][4] = (v2f){a1.x, c1.x}; wh[p][5] = (v2f){a1.y, c1.y};
      wh[p][6] = (v2f){a1.z, c1.z}; wh[p][7] = (v2f){a1.w, c1.w};
    }
    v2f wx[2][8];
    #pragma unroll
    for (int p = 0; p < 2; ++p) {
      const float* r0 = Wx1 + (size_t)(4 * ks + 2 * p) * Hn + col0;
      float4 a0 = *(const float4*)r0, a1 = *(const float4*)(r0 + 4);
      float4 c0 = *(const float4*)(r0 + Hn), c1 = *(const float4*)(r0 + Hn + 4);
      wx[p][0] = (v2f){a0.x, c0.x}; wx[p][1] = (v2f){a0.y, c0.y};
      wx[p][2] = (v2f){a0.z, c0.z}; wx[p][3] = (v2f){a0.w, c0.w};
      wx[p][4] = (v2f){a1.x, c1.x}; wx[p][5] = (v2f){a1.y, c1.y};
      wx[p][6] = (v2f){a1.z, c1.z}; wx[p][7] = (v2f){a1.w, c1.w};
    }
    const float bj = b1[jcol];
    const int sidx = (jcol >> 5) * HSL + (jcol & 31);
    const int rbase = (ks >> 1) * HSL + ((ks & 1) << 4);

    for (int i = tid; i < 2 * 8 * HSL; i += 512) hc0[i] = 0.f;
    *(float4*)&xs0[4 * tid] = *(const float4*)(xb + 4 * tid);
    __syncthreads();

    float hreg[8];
    float4 xr = make_float4(0.f, 0.f, 0.f, 0.f);
    for (int t8 = 0; t8 < 128; ++t8) {
      const int xcur = (t8 >> 2) & 1;
      #pragma unroll
      for (int s = 0; s < 8; ++s) {
        const int t = t8 * 8 + s;
        const int cu = s & 1, nx = cu ^ 1;
        if (s == 0 && (t8 & 3) == 0 && t8 < 124)
          xr = *(const float4*)(xb + (size_t)((t8 >> 2) + 1) * 2048 + 4 * tid);

        v2f a0 = (v2f){0.f, 0.f}, a1 = a0, a2 = a0, a3 = a0,
            a4 = a0, a5 = a0, a6 = a0, a7 = a0;
        const float4* h4 = (const float4*)&hc0[cu * 8 * HSL + rbase];
        #pragma unroll
        for (int qq = 0; qq < 4; ++qq) {
          float4 hv = h4[qq];
          v2f hA = (v2f){hv.x, hv.y}, hB = (v2f){hv.z, hv.w};
          a0 = __builtin_elementwise_fma(hA, wh[2*qq][0], a0);
          a1 = __builtin_elementwise_fma(hA, wh[2*qq][1], a1);
          a2 = __builtin_elementwise_fma(hA, wh[2*qq][2], a2);
          a3 = __builtin_elementwise_fma(hA, wh[2*qq][3], a3);
          a4 = __builtin_elementwise_fma(hA, wh[2*qq][4], a4);
          a5 = __builtin_elementwise_fma(hA, wh[2*qq][5], a5);
          a6 = __builtin_elementwise_fma(hA, wh[2*qq][6], a6);
          a7 = __builtin_elementwise_fma(hA, wh[2*qq][7], a7);
          a0 = __builtin_elementwise_fma(hB, wh[2*qq+1][0], a0);
          a1 = __builtin_elementwise_fma(hB, wh[2*qq+1][1], a1);
          a2 = __builtin_elementwise_fma(hB, wh[2*qq+1][2], a2);
          a3 = __builtin_elementwise_fma(hB, wh[2*qq+1][3], a3);
          a4 = __builtin_elementwise_fma(hB, wh[2*qq+1][4], a4);
          a5 = __builtin_elementwise_fma(hB, wh[2*qq+1][5], a5);
          a6 = __builtin_elementwise_fma(hB, wh[2*qq+1][6], a6);
          a7 = __builtin_elementwise_fma(hB, wh[2*qq+1][7], a7);
        }
        {
          float4 xv = *(const float4*)&xs0[xcur * 2048 + ((t & 31) << 6) + 4 * ks];
          v2f xA = (v2f){xv.x, xv.y}, xB = (v2f){xv.z, xv.w};
          a0 = __builtin_elementwise_fma(xA, wx[0][0], a0);
          a1 = __builtin_elementwise_fma(xA, wx[0][1], a1);
          a2 = __builtin_elementwise_fma(xA, wx[0][2], a2);
          a3 = __builtin_elementwise_fma(xA, wx[0][3], a3);
          a4 = __builtin_elementwise_fma(xA, wx[0][4], a4);
          a5 = __builtin_elementwise_fma(xA, wx[0][5], a5);
          a6 = __builtin_elementwise_fma(xA, wx[0][6], a6);
          a7 = __builtin_elementwise_fma(xA, wx[0][7], a7);
          a0 = __builtin_elementwise_fma(xB, wx[1][0], a0);
          a1 = __builtin_elementwise_fma(xB, wx[1][1], a1);
          a2 = __builtin_elementwise_fma(xB, wx[1][2], a2);
          a3 = __builtin_elementwise_fma(xB, wx[1][3], a3);
          a4 = __builtin_elementwise_fma(xB, wx[1][4], a4);
          a5 = __builtin_elementwise_fma(xB, wx[1][5], a5);
          a6 = __builtin_elementwise_fma(xB, wx[1][6], a6);
          a7 = __builtin_elementwise_fma(xB, wx[1][7], a7);
        }
        float s0 = row16_sum(a0.x + a0.y), s1 = row16_sum(a1.x + a1.y);
        float s2 = row16_sum(a2.x + a2.y), s3 = row16_sum(a3.x + a3.y);
        float s4 = row16_sum(a4.x + a4.y), s5 = row16_sum(a5.x + a5.y);
        float s6 = row16_sum(a6.x + a6.y), s7 = row16_sum(a7.x + a7.y);
        float h = fast_tanh(sel8(ks, s0, s1, s2, s3, s4, s5, s6, s7) + bj);
        if (writer) hc0[nx * 8 * HSL + sidx] = h;
        hreg[s] = h;
        if (s == 7) {
          if (writer) {
            float* dst = hb + (size_t)(t - 7) * Hn + jcol;
            #pragma unroll
            for (int i = 0; i < 8; ++i) dst[i * Hn] = hreg[i];
          }
          if ((t8 & 3) == 3 && t8 < 127) *(float4*)&xs0[(xcur ^ 1) * 2048 + 4 * tid] = xr;
        }
        __syncthreads();  // vmcnt(0) drained here -> safe to release below
        if (s == 7 && (t8 & 3) == 3 && tid == 0)
          __hip_atomic_store(flags + b, (t8 >> 2) + 1, __ATOMIC_RELEASE,
                             __HIP_MEMORY_SCOPE_AGENT);
      }
    }
  } else {
    // ================= ROLE B: u2 consumer =================
    const int b = blockIdx.x - Bn;
    float* ub = h1buf + (size_t)b * Tn * Hn;  // read h1, overwrite with u2
    float* hs = smem;                          // [32][8*HSL] staged h1 block

    v2f w2[8][8];  // Wx2 rows [16ks,16ks+16) x cols [col0,col0+8)
    #pragma unroll
    for (int p = 0; p < 8; ++p) {
      const float* r0 = Wx2 + (size_t)(16 * ks + 2 * p) * Hn + col0;
      float4 a0 = *(const float4*)r0, a1 = *(const float4*)(r0 + 4);
      float4 c0 = *(const float4*)(r0 + Hn), c1 = *(const float4*)(r0 + Hn + 4);
      w2[p][0] = (v2f){a0.x, c0.x}; w2[p][1] = (v2f){a0.y, c0.y};
      w2[p][2] = (v2f){a0.z, c0.z}; w2[p][3] = (v2f){a0.w, c0.w};
      w2[p][4] = (v2f){a1.x, c1.x}; w2[p][5] = (v2f){a1.y, c1.y};
      w2[p][6] = (v2f){a1.z, c1.z}; w2[p][7] = (v2f){a1.w, c1.w};
    }
    const float b2j = b2[jcol];
    const int rbase = (ks >> 1) * HSL + ((ks & 1) << 4);
    // staging map: thread loads h1[t0 + (tid>>4)][cb..cb+16), cb=(tid&15)*16
    const int lr = tid >> 4;
    const int lcb = (tid & 15) * 16;
    const int ldst = lr * 8 * HSL + (lcb >> 5) * HSL + (lcb & 31);

    float ureg[8];
    for (int blk = 0; blk < 32; ++blk) {
      if (tid == 0) {
        while (__hip_atomic_load(flags + b, __ATOMIC_ACQUIRE,
                                 __HIP_MEMORY_SCOPE_AGENT) < blk + 1)
          __builtin_amdgcn_s_sleep(8);
      }
      __syncthreads();
      {
        const float* src = ub + (size_t)(blk * 32 + lr) * Hn + lcb;
        float4 v0 = ((const float4*)src)[0];
        float4 v1 = ((const float4*)src)[1];
        float4 v2 = ((const float4*)src)[2];
        float4 v3 = ((const float4*)src)[3];
        *(float4*)&hs[ldst + 0] = v0;
        *(float4*)&hs[ldst + 4] = v1;
        *(float4*)&hs[ldst + 8] = v2;
        *(float4*)&hs[ldst + 12] = v3;
      }
      __syncthreads();
      for (int s = 0; s < 32; ++s) {
        v2f a0 = (v2f){0.f, 0.f}, a1 = a0, a2 = a0, a3 = a0,
            a4 = a0, a5 = a0, a6 = a0, a7 = a0;
        const float4* h4 = (const float4*)&hs[s * 8 * HSL + rbase];
        #pragma unroll
        for (int qq = 0; qq < 4; ++qq) {
          float4 hv = h4[qq];
          v2f hA = (v2f){hv.x, hv.y}, hB = (v2f){hv.z, hv.w};
          a0 = __builtin_elementwise_fma(hA, w2[2*qq][0], a0);
          a1 = __builtin_elementwise_fma(hA, w2[2*qq][1], a1);
          a2 = __builtin_elementwise_fma(hA, w2[2*qq][2], a2);
          a3 = __builtin_elementwise_fma(hA, w2[2*qq][3], a3);
          a4 = __builtin_elementwise_fma(hA, w2[2*qq][4], a4);
          a5 = __builtin_elementwise_fma(hA, w2[2*qq][5], a5);
          a6 = __builtin_elementwise_fma(hA, w2[2*qq][6], a6);
          a7 = __builtin_elementwise_fma(hA, w2[2*qq][7], a7);
          a0 = __builtin_elementwise_fma(hB, w2[2*qq+1][0], a0);
          a1 = __builtin_elementwise_fma(hB, w2[2*qq+1][1], a1);
          a2 = __builtin_elementwise_fma(hB, w2[2*qq+1][2], a2);
          a3 = __builtin_elementwise_fma(hB, w2[2*qq+1][3], a3);
          a4 = __builtin_elementwise_fma(hB, w2[2*qq+1][4], a4);
          a5 = __builtin_elementwise_fma(hB, w2[2*qq+1][5], a5);
          a6 = __builtin_elementwise_fma(hB, w2[2*qq+1][6], a6);
          a7 = __builtin_elementwise_fma(hB, w2[2*qq+1][7], a7);
        }
        float s0 = row16_sum(a0.x + a0.y), s1 = row16_sum(a1.x + a1.y);
        float s2 = row16_sum(a2.x + a2.y), s3 = row16_sum(a3.x + a3.y);
        float s4 = row16_sum(a4.x + a4.y), s5 = row16_sum(a5.x + a5.y);
        float s6 = row16_sum(a6.x + a6.y), s7 = row16_sum(a7.x + a7.y);
        ureg[s & 7] = sel8(ks, s0, s1, s2, s3, s4, s5, s6, s7) + b2j;
        if ((s & 7) == 7 && writer) {
          float* dst = ub + (size_t)(blk * 32 + s - 7) * Hn + jcol;
          #pragma unroll
          for (int i = 0; i < 8; ++i) dst[i * Hn] = ureg[i];
        }
      }
      __syncthreads();  // hs reuse next block
    }
  }
}

// ---------------------------------------------------------------------------
// Scan 2: h2_t = tanh(u2_t + h2_{t-1}@Wh2). Unchanged from R6.
// ---------------------------------------------------------------------------
__global__ __launch_bounds__(512, 2) void scan2_kernel(
    const float* __restrict__ U,    // [B,T,256] = h1@Wx2 + b2
    const float* __restrict__ Wh2,  // [256,256]
    float* __restrict__ hfinal) {   // [B,256]
  __shared__ alignas(16) float hc[2][8 * HSL];
  const int tid = threadIdx.x;
  const int ks = tid & 15;
  const int cg = tid >> 4;
  const int col0 = 8 * cg;
  const int b = blockIdx.x;
  const float* Ub = U + (size_t)b * Tn * Hn;

  v2f wh[8][8];
  #pragma unroll
  for (int p = 0; p < 8; ++p) {
    const float* r0 = Wh2 + (size_t)(16 * ks + 2 * p) * Hn + col0;
    float4 a0 = *(const float4*)r0, a1 = *(const float4*)(r0 + 4);
    float4 c0 = *(const float4*)(r0 + Hn), c1 = *(const float4*)(r0 + Hn + 4);
    wh[p][0] = (v2f){a0.x, c0.x}; wh[p][1] = (v2f){a0.y, c0.y};
    wh[p][2] = (v2f){a0.z, c0.z}; wh[p][3] = (v2f){a0.w, c0.w};
    wh[p][4] = (v2f){a1.x, c1.x}; wh[p][5] = (v2f){a1.y, c1.y};
    wh[p][6] = (v2f){a1.z, c1.z}; wh[p][7] = (v2f){a1.w, c1.w};
  }
  const int jcol = col0 + (ks & 7);
  const bool writer = (ks < 8);
  const int sidx = (jcol >> 5) * HSL + (jcol & 31);
  const int rbase = (ks >> 1) * HSL + ((ks & 1) << 4);

  for (int i = tid; i < 2 * 8 * HSL; i += 512) (&hc[0][0])[i] = 0.f;
  __syncthreads();

  float ucur[8], unxt[8];
  if (writer) {
    #pragma unroll
    for (int i = 0; i < 8; ++i) ucur[i] = Ub[(size_t)i * Hn + jcol];
  }

  for (int t8 = 0; t8 < 128; ++t8) {
    #pragma unroll
    for (int s = 0; s < 8; ++s) {
      const int cu = s & 1, nx = cu ^ 1;
      if (s == 0 && writer && t8 < 127) {
        #pragma unroll
        for (int i = 0; i < 8; ++i)
          unxt[i] = Ub[(size_t)(t8 * 8 + 8 + i) * Hn + jcol];
      }
      v2f a0 = (v2f){0.f, 0.f}, a1 = a0, a2 = a0, a3 = a0,
          a4 = a0, a5 = a0, a6 = a0, a7 = a0;
      const float4* h4 = (const float4*)&hc[cu][rbase];
      #pragma unroll
      for (int qq = 0; qq < 4; ++qq) {
        float4 hv = h4[qq];
        v2f hA = (v2f){hv.x, hv.y}, hB = (v2f){hv.z, hv.w};
        a0 = __builtin_elementwise_fma(hA, wh[2*qq][0], a0);
        a1 = __builtin_elementwise_fma(hA, wh[2*qq][1], a1);
        a2 = __builtin_elementwise_fma(hA, wh[2*qq][2], a2);
        a3 = __builtin_elementwise_fma(hA, wh[2*qq][3], a3);
        a4 = __builtin_elementwise_fma(hA, wh[2*qq][4], a4);
        a5 = __builtin_elementwise_fma(hA, wh[2*qq][5], a5);
        a6 = __builtin_elementwise_fma(hA, wh[2*qq][6], a6);
        a7 = __builtin_elementwise_fma(hA, wh[2*qq][7], a7);
        a0 = __builtin_elementwise_fma(hB, wh[2*qq+1][0], a0);
        a1 = __builtin_elementwise_fma(hB, wh[2*qq+1][1], a1);
        a2 = __builtin_elementwise_fma(hB, wh[2*qq+1][2], a2);
        a3 = __builtin_elementwise_fma(hB, wh[2*qq+1][3], a3);
        a4 = __builtin_elementwise_fma(hB, wh[2*qq+1][4], a4);
        a5 = __builtin_elementwise_fma(hB, wh[2*qq+1][5], a5);
        a6 = __builtin_elementwise_fma(hB, wh[2*qq+1][6], a6);
        a7 = __builtin_elementwise_fma(hB, wh[2*qq+1][7], a7);
      }
      float s0 = row16_sum(a0.x + a0.y), s1 = row16_sum(a1.x + a1.y);
      float s2 = row16_sum(a2.x + a2.y), s3 = row16_sum(a3.x + a3.y);
      float s4 = row16_sum(a4.x + a4.y), s5 = row16_sum(a5.x + a5.y);
      float s6 = row16_sum(a6.x + a6.y), s7 = row16_sum(a7.x + a7.y);
      float h = fast_tanh(sel8(ks, s0, s1, s2, s3, s4, s5, s6, s7) + ucur[s]);
      if (writer) hc[nx][sidx] = h;
      if (s == 7) {
        #pragma unroll
        for (int i = 0; i < 8; ++i) ucur[i] = unxt[i];
      }
      __syncthreads();
    }
  }
  if (tid < Hn)
    hfinal[(size_t)b * Hn + tid] = hc[0][(tid >> 5) * HSL + (tid & 31)];
}

// ---------------------------------------------------------------------------
// Head: out = softmax(h2_T @ Wd + bd). Unchanged.
// ---------------------------------------------------------------------------
__global__ __launch_bounds__(128) void head_kernel(
    const float* __restrict__ hfinal, const float* __restrict__ Wd,
    const float* __restrict__ bd, float* __restrict__ out) {
  __shared__ float hrow[Hn];
  __shared__ float red[On];
  const int o = threadIdx.x;
  const int b = blockIdx.x;
  hrow[o] = hfinal[(size_t)b * Hn + o];
  hrow[o + 128] = hfinal[(size_t)b * Hn + 128 + o];
  __syncthreads();
  float acc = bd[o];
  #pragma unroll 8
  for (int k = 0; k < Hn; ++k) acc = fmaf(hrow[k], Wd[(size_t)k * On + o], acc);
  red[o] = acc;
  __syncthreads();
  #pragma unroll
  for (int s = 64; s > 0; s >>= 1) {
    if (o < s) red[o] = fmaxf(red[o], red[o + s]);
    __syncthreads();
  }
  const float mx = red[0];
  __syncthreads();
  const float e = __expf(acc - mx);
  red[o] = e;
  __syncthreads();
  #pragma unroll
  for (int s = 64; s > 0; s >>= 1) {
    if (o < s) red[o] += red[o + s];
    __syncthreads();
  }
  out[(size_t)b * On + o] = e / red[0];
}

// ---------------------------------------------------------------------------
extern "C" void kernel_launch(void* const* d_in, const int* in_sizes, int n_in,
                              void* d_out, int out_size, void* d_ws, size_t ws_size,
                              hipStream_t stream) {
  const float* x   = (const float*)d_in[0];
  const float* Wx1 = (const float*)d_in[1];
  const float* Wh1 = (const float*)d_in[2];
  const float* b1  = (const float*)d_in[3];
  const float* Wx2 = (const float*)d_in[4];
  const float* Wh2 = (const float*)d_in[5];
  const float* b2  = (const float*)d_in[6];
  const float* Wd  = (const float*)d_in[7];
  const float* bd  = (const float*)d_in[8];
  float* out = (float*)d_out;

  float* buf = (float*)d_ws;                   // h1 -> (in-place) u2: [B*T*256]
  float* hfinal = buf + (size_t)Bn * Tn * Hn;  // [B*256]
  int* flags = (int*)(hfinal + (size_t)Bn * Hn);  // [B]

  hipMemsetAsync(flags, 0, Bn * sizeof(int), stream);
  stage1_kernel<<<2 * Bn, 512, 0, stream>>>(x, Wx1, Wh1, b1, Wx2, b2, buf, flags);
  scan2_kernel<<<Bn, 512, 0, stream>>>(buf, Wh2, hfinal);
  head_kernel<<<Bn, 128, 0, stream>>>(hfinal, Wd, bd, out);
}